// Round 8
// baseline (84.804 us; speedup 1.0000x reference)
//
#include <hip/hip_runtime.h>

typedef unsigned int   u32;
typedef unsigned short u16;
typedef _Float16       f16;

using f16x8  = __attribute__((ext_vector_type(8)))  _Float16;
using f32x16 = __attribute__((ext_vector_type(16))) float;

#define LLDS16(G, L) __builtin_amdgcn_global_load_lds( \
  (const __attribute__((address_space(1))) u32*)(G), \
  (__attribute__((address_space(3))) u32*)(L), 16, 0, 0)

#define WAITV(N) { asm volatile("s_waitcnt vmcnt(" #N ")" ::: "memory"); \
                   __builtin_amdgcn_sched_barrier(0); }
#define FENCE_BAR() { asm volatile("s_waitcnt lgkmcnt(0)" ::: "memory"); \
                      __builtin_amdgcn_sched_barrier(0); \
                      __builtin_amdgcn_s_barrier(); \
                      __builtin_amdgcn_sched_barrier(0); }
#define BAR() { __builtin_amdgcn_s_barrier(); __builtin_amdgcn_sched_barrier(0); }
#define KEEP(x) asm volatile("" : "+v"(x))

// ---- merged prep: [bid<2560] x transpose+sums; [else] W0/W1 k-panel ----
__global__ __launch_bounds__(256)
void prep(const float* __restrict__ x,
          const float* __restrict__ W0, const float* __restrict__ W1,
          f16* __restrict__ xt, f16* __restrict__ W0p, f16* __restrict__ W1p,
          float* __restrict__ out){
  __shared__ char shm[33920];
  const int tid = threadIdx.x;
  if (blockIdx.x < 2560){
    // x (81920,32) f32 -> (32,81920) f16, plus out[b][f] = sum_d
    float (*tile)[33] = (float(*)[33])shm;
    const int r0 = blockIdx.x << 5;
    const int c  = tid & 31;
    const int rp = tid >> 5;
#pragma unroll
    for (int p = 0; p < 4; ++p){
      const int r = (p << 3) + rp;
      float v = x[(size_t)(r0 + r) * 32 + c];
      tile[r][c] = v;
      float s = v;
#pragma unroll
      for (int off = 16; off > 0; off >>= 1) s += __shfl_xor(s, off, 32);
      if (c == 0){
        const int row = r0 + r;            // = b*40 + f
        out[(size_t)(row / 40) * 168 + (row % 40)] = s;
      }
    }
    __syncthreads();
#pragma unroll
    for (int p = 0; p < 4; ++p){
      const int dd = (p << 3) + rp;
      xt[(size_t)dd * 81920 + r0 + c] = (f16)tile[c][dd];
    }
  } else {
    // W (64,K,32) f32 -> [32][K/8][64][8] f16 k-panels
    u16* t = (u16*)shm;
    int kb = blockIdx.x - 2560;
    const float* in; f16* outp; int K;
    if (kb < 200){ in = W0; outp = W0p; K = 1600; }
    else         { kb -= 200; in = W1; outp = W1p; K = 2560; }
    const int kbase = kb << 3;
#pragma unroll 4
    for (int i = 0; i < 64; ++i){
      const int idx = tid + (i << 8);
      const int o   = idx >> 8;
      const int rem = idx & 255;
      const int e   = rem >> 5;
      const int dd  = rem & 31;
      const float v = in[(size_t)o * (K * 32) + (size_t)(kbase + e) * 32 + dd];
      union { f16 h; u16 u; } cv; cv.h = (f16)v;
      t[dd * 530 + o * 8 + e] = cv.u;
    }
    __syncthreads();
    const u32* t32 = (const u32*)t;
    u32* o32 = (u32*)outp;
    const int obase = kb << 8;
#pragma unroll 4
    for (int i = 0; i < 32; ++i){
      const int idx = tid + (i << 8);
      const int dd  = idx >> 8;
      const int rem = idx & 255;
      o32[(size_t)dd * (K * 32) + obase + rem] = t32[dd * 265 + rem];
    }
  }
}

// -------- fused CIN: phase1 (K=1600) -> x1 in LDS -> phase2 (K=2560) --------
// Block: 256 rows x 64 cols x one d, 8 waves.  Wave: 64 rows (2 strips) x 32.
// 13 B-tiles (5 W0 + 8 W1) stream through one dbuf pipeline, counted vmcnt.
// d-sums of x1 and y2 accumulate into out via atomicAdd (out pre-zeroed).
__global__ __launch_bounds__(512, 1)
void cin_fused(const f16* __restrict__ xt,     // [32][2048*40] f16
               const f16* __restrict__ W0p,    // [32][200][64][8] f16
               const f16* __restrict__ W1p,    // [32][320][64][8] f16
               const float* __restrict__ b0v, const float* __restrict__ b1v,
               float* __restrict__ out){
  constexpr int X0OFF = 81920;          // after 2x40KB B dbuf
  constexpr int X1OFF = 110592;         // X0OFF + 256*112
  constexpr int X0MS  = 32 * 112;
  constexpr int X1MS  = 32 * 144;

  const int bid = blockIdx.x;
  const int d   = ((bid & 7) << 2) | ((bid >> 3) & 3);   // XCD-local d groups
  const int b0  = (bid >> 5) << 8;
  const int tid = threadIdx.x;
  const int wv  = tid >> 6;
  const int wr  = wv >> 1;              // row quarter (64 rows)
  const int wc  = wv & 1;               // col half
  const int l   = tid & 63;
  const int hi  = l >> 5;
  const int lr  = l & 31;

  __shared__ char smem[147456];

  const f16* gW0 = W0p + (size_t)d * 102400;
  const f16* gW1 = W1p + (size_t)d * 163840;

#define ISSUE(I) do { \
    const f16* src_ = ((I) < 5) ? (gW0 + (size_t)(I) * 20480) \
                                : (gW1 + (size_t)((I) - 5) * 20480); \
    const f16* gt_ = src_ + wv * 2560 + l * 8; \
    char* lb_ = smem + ((I) & 1) * 40960 + wv * 5120; \
    _Pragma("unroll") \
    for (int j_ = 0; j_ < 5; ++j_) LLDS16(gt_ + j_ * 512, lb_ + j_ * 1024); \
  } while (0)

  ISSUE(0);
  ISSUE(1);

  { // stage x0 tile: 256 rows * 80B -> stride 112B
    const uint4* src = (const uint4*)(xt + (size_t)d * 81920 + (size_t)b0 * 40);
#pragma unroll
    for (int it = 0; it < 3; ++it){
      const int idx = tid + (it << 9);
      if (idx < 1280){
        const int r = idx / 5, c = idx - r * 5;
        *(uint4*)(smem + X0OFF + r * 112 + c * 16) = src[idx];
      }
    }
  }
  __syncthreads();                      // drains vmcnt: tiles 0,1 + x0 landed

  const char* x0row = smem + X0OFF + (wr * 64 + lr) * 112;
  const char* x1row = smem + X1OFF + (wr * 64 + lr) * 144;
  const int   hcol  = (wc << 5) + lr;
  const float bv1   = b0v[hcol];
  const float bv2   = b1v[hcol];

  // sl[m][t] = x0 f-block (t+hi)%5 of strip-m row (pinned; shared by phases)
  f16x8 sl[2][5];
#pragma unroll
  for (int m = 0; m < 2; ++m){
    const char* xe = x0row + m * X0MS + hi * 16;
#pragma unroll
    for (int t = 0; t < 4; ++t) sl[m][t] = *(const f16x8*)(xe + t * 16);
    sl[m][4] = *(const f16x8*)(x0row + m * X0MS + (hi ? 0 : 64));
  }
  KEEP(sl[0][0]); KEEP(sl[0][1]); KEEP(sl[0][2]); KEEP(sl[0][3]); KEEP(sl[0][4]);
  KEEP(sl[1][0]); KEEP(sl[1][1]); KEEP(sl[1][2]); KEEP(sl[1][3]); KEEP(sl[1][4]);

  f32x16 acc0 = {0,0,0,0,0,0,0,0,0,0,0,0,0,0,0,0};
  f32x16 acc1 = {0,0,0,0,0,0,0,0,0,0,0,0,0,0,0,0};

  const int vb = hi * 1024 + wc * 512 + lr * 16;

  // k-run r8 = si*4 + kh*2 + hi; j = r8%5 (hi-rotated sl), h = r8/5
  static constexpr int J0[10]  = {0,4,3,2,1,0,4,3,2,1};
  static constexpr int H0[10]  = {0,0,1,2,3,4,4,5,6,7};
  static constexpr int H0b[10] = {0,1,1,2,3,4,5,5,6,7};
  static constexpr int S0[10]  = {0,1,0,0,0,0,1,0,0,0};
  static constexpr int J2[10]  = {2,1,0,4,3,2,1,0,4,3};
  static constexpr int H2[10]  = {0,1,2,2,3,4,5,6,6,7};
  static constexpr int H2b[10] = {0,1,2,3,3,4,5,6,7,7};
  static constexpr int S2[10]  = {0,0,0,1,0,0,0,0,1,0};

#define COMP(BB) do { \
  _Pragma("unroll") \
  for (int si = 0; si < 10; ++si){ \
    const f16x8 bf0 = *(const f16x8*)((BB) + (si * 4) * 1024); \
    const f16x8 bf2 = *(const f16x8*)((BB) + (si * 4 + 2) * 1024); \
    const f16 xa00 = (S0[si] && hi) ? xh0[H0b[si]] : xh0[H0[si]]; \
    const f16 xa01 = (S0[si] && hi) ? xh1[H0b[si]] : xh1[H0[si]]; \
    const f16 xa20 = (S2[si] && hi) ? xh0[H2b[si]] : xh0[H2[si]]; \
    const f16 xa21 = (S2[si] && hi) ? xh1[H2b[si]] : xh1[H2[si]]; \
    acc0 = __builtin_amdgcn_mfma_f32_32x32x16_f16(sl[0][J0[si]] * xa00, bf0, acc0, 0, 0, 0); \
    acc1 = __builtin_amdgcn_mfma_f32_32x32x16_f16(sl[1][J0[si]] * xa01, bf0, acc1, 0, 0, 0); \
    acc0 = __builtin_amdgcn_mfma_f32_32x32x16_f16(sl[0][J2[si]] * xa20, bf2, acc0, 0, 0, 0); \
    acc1 = __builtin_amdgcn_mfma_f32_32x32x16_f16(sl[1][J2[si]] * xa21, bf2, acc1, 0, 0, 0); \
  } \
} while (0)

  // ---------------- phase 1: xk = x0, 5 tiles ----------------
  {
    f16x8 xh0 = *(const f16x8*)(x0row);
    f16x8 xh1 = *(const f16x8*)(x0row + X0MS);
    for (int t = 0; t < 5; ++t){
      const char* bb = smem + (t & 1) * 40960 + vb;
      const f16x8 xhn0 = *(const f16x8*)(x0row + (t + 1) * 16);        // pad-safe
      const f16x8 xhn1 = *(const f16x8*)(x0row + X0MS + (t + 1) * 16);
      COMP(bb);
      FENCE_BAR();
      ISSUE(t + 2);                     // t+2 in 2..6 (5,6 are W1 tiles 0,1)
      WAITV(5);                         // tile t+1 landed
      BAR();
      xh0 = xhn0; xh1 = xhn1;
    }
  }

  // ---- epilogue 1: x1 -> LDS tile (+ d-sum atomics), reset acc ----
  {
    u16* x1w = (u16*)(smem + X1OFF);
#pragma unroll
    for (int m = 0; m < 2; ++m)
#pragma unroll
      for (int reg = 0; reg < 16; ++reg){
        const int row = (wr << 6) + (m << 5) + (reg & 3) + ((reg >> 2) << 3) + (hi << 2);
        float v = (m ? acc1[reg] : acc0[reg]) + bv1;
        v = v > 0.f ? v : 0.f;
        union { f16 h; u16 u; } cv; cv.h = (f16)v;
        x1w[row * 72 + hcol] = cv.u;
        atomicAdd(&out[(size_t)(b0 + row) * 168 + 40 + hcol], v);
      }
    const f32x16 fz = {0,0,0,0,0,0,0,0,0,0,0,0,0,0,0,0};
    acc0 = fz; acc1 = fz;
    asm volatile("s_waitcnt lgkmcnt(0)" ::: "memory");
    __builtin_amdgcn_sched_barrier(0);
    WAITV(0);                           // drain atomics + tile 6 (reset count)
    BAR();                              // x1 tile visible to all waves
  }

  // ---------------- phase 2: xk = x1 (LDS), 8 tiles ----------------
  {
    f16x8 xh0 = *(const f16x8*)(x1row);
    f16x8 xh1 = *(const f16x8*)(x1row + X1MS);
    for (int t = 0; t < 8; ++t){
      const char* bb = smem + ((t + 1) & 1) * 40960 + vb;
      const f16x8 xhn0 = *(const f16x8*)(x1row + (t + 1) * 16);        // pad-safe
      const f16x8 xhn1 = *(const f16x8*)(x1row + X1MS + (t + 1) * 16);
      COMP(bb);
      FENCE_BAR();
      if (t + 2 < 8){
        ISSUE(5 + t + 2);
        WAITV(5);
      } else {
        WAITV(0);
      }
      BAR();
      xh0 = xhn0; xh1 = xhn1;
    }
  }

  // ---- epilogue 2: y2 d-sum atomics ----
#pragma unroll
  for (int m = 0; m < 2; ++m)
#pragma unroll
    for (int reg = 0; reg < 16; ++reg){
      const int row = (wr << 6) + (m << 5) + (reg & 3) + ((reg >> 2) << 3) + (hi << 2);
      float v = (m ? acc1[reg] : acc0[reg]) + bv2;
      v = v > 0.f ? v : 0.f;
      atomicAdd(&out[(size_t)(b0 + row) * 168 + 104 + hcol], v);
    }
#undef ISSUE
#undef COMP
}

extern "C" void kernel_launch(void* const* d_in, const int* in_sizes, int n_in,
                              void* d_out, int out_size, void* d_ws, size_t ws_size,
                              hipStream_t stream){
  const float* x   = (const float*)d_in[0];
  const float* W0  = (const float*)d_in[1];
  const float* b0v = (const float*)d_in[2];
  const float* W1  = (const float*)d_in[3];
  const float* b1v = (const float*)d_in[4];
  float* out = (float*)d_out;

  char* ws = (char*)d_ws;
  f16* xt  = (f16*)(ws + 0);            // 32*2048*40*2  =  5,242,880
  f16* W0p = (f16*)(ws + 5242880);      // 32*64*1600*2  =  6,553,600
  f16* W1p = (f16*)(ws + 11796480);     // 32*64*2560*2  = 10,485,760

  hipMemsetAsync(out, 0, (size_t)2048 * 168 * sizeof(float), stream);
  prep<<<3080, 256, 0, stream>>>(x, W0, W1, xt, W0p, W1p, out);
  cin_fused<<<256, 512, 0, stream>>>(xt, W0p, W1p, b0v, b1v, out);
}

// Round 9
// 59.474 us; speedup vs baseline: 1.4259x; 1.4259x over previous
//
#include <hip/hip_runtime.h>

typedef unsigned int   u32;
typedef unsigned short u16;
typedef _Float16       f16;

using f16x8  = __attribute__((ext_vector_type(8)))  _Float16;
using f32x16 = __attribute__((ext_vector_type(16))) float;

#define LLDS16(G, L) __builtin_amdgcn_global_load_lds( \
  (const __attribute__((address_space(1))) u32*)(G), \
  (__attribute__((address_space(3))) u32*)(L), 16, 0, 0)

#define WAITV(N) { asm volatile("s_waitcnt vmcnt(" #N ")" ::: "memory"); \
                   __builtin_amdgcn_sched_barrier(0); }
#define FENCE_BAR() { asm volatile("s_waitcnt lgkmcnt(0)" ::: "memory"); \
                      __builtin_amdgcn_sched_barrier(0); \
                      __builtin_amdgcn_s_barrier(); \
                      __builtin_amdgcn_sched_barrier(0); }
#define BAR() { __builtin_amdgcn_s_barrier(); __builtin_amdgcn_sched_barrier(0); }
#define KEEP(x) asm volatile("" : "+v"(x))

// ---- merged prep: [bid<2560] x transpose+sums; [else] W0/W1 k-panel ----
__global__ __launch_bounds__(256)
void prep(const float* __restrict__ x,
          const float* __restrict__ W0, const float* __restrict__ W1,
          f16* __restrict__ xt, f16* __restrict__ W0p, f16* __restrict__ W1p,
          float* __restrict__ out){
  __shared__ char shm[33920];
  const int tid = threadIdx.x;
  if (blockIdx.x < 2560){
    // x (81920,32) f32 -> (32,81920) f16, plus out[b][f] = sum_d
    float (*tile)[33] = (float(*)[33])shm;
    const int r0 = blockIdx.x << 5;
    const int c  = tid & 31;
    const int rp = tid >> 5;
#pragma unroll
    for (int p = 0; p < 4; ++p){
      const int r = (p << 3) + rp;
      float v = x[(size_t)(r0 + r) * 32 + c];
      tile[r][c] = v;
      float s = v;
#pragma unroll
      for (int off = 16; off > 0; off >>= 1) s += __shfl_xor(s, off, 32);
      if (c == 0){
        const int row = r0 + r;            // = b*40 + f
        out[(size_t)(row / 40) * 168 + (row % 40)] = s;
      }
    }
    __syncthreads();
#pragma unroll
    for (int p = 0; p < 4; ++p){
      const int dd = (p << 3) + rp;
      xt[(size_t)dd * 81920 + r0 + c] = (f16)tile[c][dd];
    }
  } else {
    // W (64,K,32) f32 -> [32][K/8][64][8] f16 k-panels
    u16* t = (u16*)shm;
    int kb = blockIdx.x - 2560;
    const float* in; f16* outp; int K;
    if (kb < 200){ in = W0; outp = W0p; K = 1600; }
    else         { kb -= 200; in = W1; outp = W1p; K = 2560; }
    const int kbase = kb << 3;
#pragma unroll 4
    for (int i = 0; i < 64; ++i){
      const int idx = tid + (i << 8);
      const int o   = idx >> 8;
      const int rem = idx & 255;
      const int e   = rem >> 5;
      const int dd  = rem & 31;
      const float v = in[(size_t)o * (K * 32) + (size_t)(kbase + e) * 32 + dd];
      union { f16 h; u16 u; } cv; cv.h = (f16)v;
      t[dd * 530 + o * 8 + e] = cv.u;
    }
    __syncthreads();
    const u32* t32 = (const u32*)t;
    u32* o32 = (u32*)outp;
    const int obase = kb << 8;
#pragma unroll 4
    for (int i = 0; i < 32; ++i){
      const int idx = tid + (i << 8);
      const int dd  = idx >> 8;
      const int rem = idx & 255;
      o32[(size_t)dd * (K * 32) + obase + rem] = t32[dd * 265 + rem];
    }
  }
}

// -------- fused CIN: phase1 (K=1600) -> x1 in LDS -> phase2 (K=2560) --------
// Block: 256 rows x 64 cols x one d, 8 waves.  Wave: 64 rows (2 strips) x 32.
// 13 B-tiles (5 W0 + 8 W1) stream through one dbuf pipeline, counted vmcnt.
// Partial outputs written coalesced to x1s/y2s in [b][d][o]; no atomics.
__global__ __launch_bounds__(512, 1)
void cin_fused(const f16* __restrict__ xt,     // [32][2048*40] f16
               const f16* __restrict__ W0p,    // [32][200][64][8] f16
               const f16* __restrict__ W1p,    // [32][320][64][8] f16
               const float* __restrict__ b0v, const float* __restrict__ b1v,
               f16* __restrict__ x1s,          // [2048][32][64] f16
               f16* __restrict__ y2s){         // [2048][32][64] f16
  constexpr int X0OFF = 81920;          // after 2x40KB B dbuf
  constexpr int X1OFF = 110592;         // X0OFF + 256*112
  constexpr int X0MS  = 32 * 112;
  constexpr int X1MS  = 32 * 144;

  const int bid = blockIdx.x;
  const int d   = ((bid & 7) << 2) | ((bid >> 3) & 3);   // XCD-local d groups
  const int b0  = (bid >> 5) << 8;
  const int tid = threadIdx.x;
  const int wv  = tid >> 6;
  const int wr  = wv >> 1;              // row quarter (64 rows)
  const int wc  = wv & 1;               // col half
  const int l   = tid & 63;
  const int hi  = l >> 5;
  const int lr  = l & 31;

  __shared__ char smem[147456];

  const f16* gW0 = W0p + (size_t)d * 102400;
  const f16* gW1 = W1p + (size_t)d * 163840;

#define ISSUE(I) do { \
    const f16* src_ = ((I) < 5) ? (gW0 + (size_t)(I) * 20480) \
                                : (gW1 + (size_t)((I) - 5) * 20480); \
    const f16* gt_ = src_ + wv * 2560 + l * 8; \
    char* lb_ = smem + ((I) & 1) * 40960 + wv * 5120; \
    _Pragma("unroll") \
    for (int j_ = 0; j_ < 5; ++j_) LLDS16(gt_ + j_ * 512, lb_ + j_ * 1024); \
  } while (0)

  ISSUE(0);
  ISSUE(1);

  { // stage x0 tile: 256 rows * 80B -> stride 112B
    const uint4* src = (const uint4*)(xt + (size_t)d * 81920 + (size_t)b0 * 40);
#pragma unroll
    for (int it = 0; it < 3; ++it){
      const int idx = tid + (it << 9);
      if (idx < 1280){
        const int r = idx / 5, c = idx - r * 5;
        *(uint4*)(smem + X0OFF + r * 112 + c * 16) = src[idx];
      }
    }
  }
  __syncthreads();                      // drains vmcnt: tiles 0,1 + x0 landed

  const char* x0row = smem + X0OFF + (wr * 64 + lr) * 112;
  const char* x1row = smem + X1OFF + (wr * 64 + lr) * 144;
  const int   hcol  = (wc << 5) + lr;
  const float bv1   = b0v[hcol];
  const float bv2   = b1v[hcol];

  // sl[m][t] = x0 f-block (t+hi)%5 of strip-m row (pinned; shared by phases)
  f16x8 sl[2][5];
#pragma unroll
  for (int m = 0; m < 2; ++m){
    const char* xe = x0row + m * X0MS + hi * 16;
#pragma unroll
    for (int t = 0; t < 4; ++t) sl[m][t] = *(const f16x8*)(xe + t * 16);
    sl[m][4] = *(const f16x8*)(x0row + m * X0MS + (hi ? 0 : 64));
  }
  KEEP(sl[0][0]); KEEP(sl[0][1]); KEEP(sl[0][2]); KEEP(sl[0][3]); KEEP(sl[0][4]);
  KEEP(sl[1][0]); KEEP(sl[1][1]); KEEP(sl[1][2]); KEEP(sl[1][3]); KEEP(sl[1][4]);

  f32x16 acc0 = {0,0,0,0,0,0,0,0,0,0,0,0,0,0,0,0};
  f32x16 acc1 = {0,0,0,0,0,0,0,0,0,0,0,0,0,0,0,0};

  const int vb = hi * 1024 + wc * 512 + lr * 16;

  // k-run r8 = si*4 + kh*2 + hi; j = r8%5 (hi-rotated sl), h = r8/5
  static constexpr int J0[10]  = {0,4,3,2,1,0,4,3,2,1};
  static constexpr int H0[10]  = {0,0,1,2,3,4,4,5,6,7};
  static constexpr int H0b[10] = {0,1,1,2,3,4,5,5,6,7};
  static constexpr int S0[10]  = {0,1,0,0,0,0,1,0,0,0};
  static constexpr int J2[10]  = {2,1,0,4,3,2,1,0,4,3};
  static constexpr int H2[10]  = {0,1,2,2,3,4,5,6,6,7};
  static constexpr int H2b[10] = {0,1,2,3,3,4,5,6,7,7};
  static constexpr int S2[10]  = {0,0,0,1,0,0,0,0,1,0};

#define COMP(BB) do { \
  _Pragma("unroll") \
  for (int si = 0; si < 10; ++si){ \
    const f16x8 bf0 = *(const f16x8*)((BB) + (si * 4) * 1024); \
    const f16x8 bf2 = *(const f16x8*)((BB) + (si * 4 + 2) * 1024); \
    const f16 xa00 = (S0[si] && hi) ? xh0[H0b[si]] : xh0[H0[si]]; \
    const f16 xa01 = (S0[si] && hi) ? xh1[H0b[si]] : xh1[H0[si]]; \
    const f16 xa20 = (S2[si] && hi) ? xh0[H2b[si]] : xh0[H2[si]]; \
    const f16 xa21 = (S2[si] && hi) ? xh1[H2b[si]] : xh1[H2[si]]; \
    acc0 = __builtin_amdgcn_mfma_f32_32x32x16_f16(sl[0][J0[si]] * xa00, bf0, acc0, 0, 0, 0); \
    acc1 = __builtin_amdgcn_mfma_f32_32x32x16_f16(sl[1][J0[si]] * xa01, bf0, acc1, 0, 0, 0); \
    acc0 = __builtin_amdgcn_mfma_f32_32x32x16_f16(sl[0][J2[si]] * xa20, bf2, acc0, 0, 0, 0); \
    acc1 = __builtin_amdgcn_mfma_f32_32x32x16_f16(sl[1][J2[si]] * xa21, bf2, acc1, 0, 0, 0); \
  } \
} while (0)

  // ---------------- phase 1: xk = x0, 5 tiles ----------------
  {
    f16x8 xh0 = *(const f16x8*)(x0row);
    f16x8 xh1 = *(const f16x8*)(x0row + X0MS);
    for (int t = 0; t < 5; ++t){
      const char* bb = smem + (t & 1) * 40960 + vb;
      const f16x8 xhn0 = *(const f16x8*)(x0row + (t + 1) * 16);        // pad-safe
      const f16x8 xhn1 = *(const f16x8*)(x0row + X0MS + (t + 1) * 16);
      COMP(bb);
      FENCE_BAR();
      ISSUE(t + 2);                     // t+2 in 2..6 (5,6 are W1 tiles 0,1)
      WAITV(5);                         // tile t+1 landed
      BAR();
      xh0 = xhn0; xh1 = xhn1;
    }
  }

  // ---- epilogue 1: x1 -> LDS tile, reset acc, coalesced partial store ----
  {
    u16* x1w = (u16*)(smem + X1OFF);
#pragma unroll
    for (int m = 0; m < 2; ++m)
#pragma unroll
      for (int reg = 0; reg < 16; ++reg){
        const int row = (wr << 6) + (m << 5) + (reg & 3) + ((reg >> 2) << 3) + (hi << 2);
        float v = (m ? acc1[reg] : acc0[reg]) + bv1;
        v = v > 0.f ? v : 0.f;
        union { f16 h; u16 u; } cv; cv.h = (f16)v;
        x1w[row * 72 + hcol] = cv.u;
      }
    const f32x16 fz = {0,0,0,0,0,0,0,0,0,0,0,0,0,0,0,0};
    acc0 = fz; acc1 = fz;
    asm volatile("s_waitcnt lgkmcnt(0)" ::: "memory");
    __builtin_amdgcn_sched_barrier(0);
    WAITV(0);                           // drain tile 6 (reset count)
    BAR();                              // x1 tile visible to all waves
    // coalesced x1 partial store: [b][d][o] layout, 16B granules
#pragma unroll
    for (int it = 0; it < 4; ++it){
      const int u   = tid + (it << 9);
      const int row = u >> 3, ch = u & 7;
      const f16x8 vv = *(const f16x8*)((const char*)x1w + row * 144 + ch * 16);
      *(f16x8*)(x1s + (size_t)(b0 + row) * 2048 + d * 64 + ch * 8) = vv;
    }
  }

  // ---------------- phase 2: xk = x1 (LDS), 8 tiles ----------------
  {
    f16x8 xh0 = *(const f16x8*)(x1row);
    f16x8 xh1 = *(const f16x8*)(x1row + X1MS);
    for (int t = 0; t < 8; ++t){
      const char* bb = smem + ((t + 1) & 1) * 40960 + vb;
      const f16x8 xhn0 = *(const f16x8*)(x1row + (t + 1) * 16);        // pad-safe
      const f16x8 xhn1 = *(const f16x8*)(x1row + X1MS + (t + 1) * 16);
      COMP(bb);
      FENCE_BAR();
      if (t + 2 < 8){
        ISSUE(5 + t + 2);
        WAITV(5);
      } else {
        WAITV(0);
      }
      BAR();
      xh0 = xhn0; xh1 = xhn1;
    }
  }

  // ---- epilogue 2: y2 -> LDS tile -> coalesced partial store ----
  {
    u16* yw = (u16*)(smem + X1OFF);     // x1 tile no longer needed
#pragma unroll
    for (int m = 0; m < 2; ++m)
#pragma unroll
      for (int reg = 0; reg < 16; ++reg){
        const int row = (wr << 6) + (m << 5) + (reg & 3) + ((reg >> 2) << 3) + (hi << 2);
        float v = (m ? acc1[reg] : acc0[reg]) + bv2;
        v = v > 0.f ? v : 0.f;
        union { f16 h; u16 u; } cv; cv.h = (f16)v;
        yw[row * 72 + hcol] = cv.u;
      }
    asm volatile("s_waitcnt lgkmcnt(0)" ::: "memory");
    __builtin_amdgcn_sched_barrier(0);
    BAR();
#pragma unroll
    for (int it = 0; it < 4; ++it){
      const int u   = tid + (it << 9);
      const int row = u >> 3, ch = u & 7;
      const f16x8 vv = *(const f16x8*)((const char*)yw + row * 144 + ch * 16);
      *(f16x8*)(y2s + (size_t)(b0 + row) * 2048 + d * 64 + ch * 8) = vv;
    }
  }
#undef ISSUE
#undef COMP
}

// ------- final: out[b, 40:168] = sum_d concat(x1, y2), coalesced reads -------
__global__ __launch_bounds__(128)
void finalize(const f16* __restrict__ x1s, const f16* __restrict__ y2s,
              float* __restrict__ out){
  const int b = blockIdx.x;
  const int t = threadIdx.x;
  if (t < 64){
    float s = 0.f;
#pragma unroll
    for (int d = 0; d < 32; ++d) s += (float)x1s[(size_t)b * 2048 + d * 64 + t];
    out[(size_t)b * 168 + 40 + t] = s;
  } else {
    const int o = t - 64;
    float s = 0.f;
#pragma unroll
    for (int d = 0; d < 32; ++d) s += (float)y2s[(size_t)b * 2048 + d * 64 + o];
    out[(size_t)b * 168 + 104 + o] = s;
  }
}

extern "C" void kernel_launch(void* const* d_in, const int* in_sizes, int n_in,
                              void* d_out, int out_size, void* d_ws, size_t ws_size,
                              hipStream_t stream){
  const float* x   = (const float*)d_in[0];
  const float* W0  = (const float*)d_in[1];
  const float* b0v = (const float*)d_in[2];
  const float* W1  = (const float*)d_in[3];
  const float* b1v = (const float*)d_in[4];
  float* out = (float*)d_out;

  char* ws = (char*)d_ws;
  f16* xt  = (f16*)(ws + 0);            // 32*2048*40*2  =  5,242,880
  f16* W0p = (f16*)(ws + 5242880);      // 32*64*1600*2  =  6,553,600
  f16* W1p = (f16*)(ws + 11796480);     // 32*64*2560*2  = 10,485,760
  f16* x1s = (f16*)(ws + 22282240);     // 2048*32*64*2  =  8,388,608
  f16* y2s = (f16*)(ws + 30670848);     // 2048*32*64*2  =  8,388,608

  prep<<<3080, 256, 0, stream>>>(x, W0, W1, xt, W0p, W1p, out);
  cin_fused<<<256, 512, 0, stream>>>(xt, W0p, W1p, b0v, b1v, x1s, y2s);
  finalize<<<2048, 128, 0, stream>>>(x1s, y2s, out);
}